// Round 5
// baseline (39256.030 us; speedup 1.0000x reference)
//
#include <hip/hip_runtime.h>

#define B_  128
#define S_  256
#define E_  300
#define H_  512
#define G_  2048   // 4*H
#define D1_ 1024   // 2*H
#define KA_ 832    // 320 (x pad) + 512 (h)
#define LDA_ 840   // KA_ + 8 pad (LDS bank rotation)
#define LDC_ 520   // H_ + 8 pad

typedef _Float16 f16;
typedef __attribute__((ext_vector_type(8))) _Float16 f16x8;
typedef __attribute__((ext_vector_type(4))) float    f32x4;

__device__ __forceinline__ float sigf(float x){ return 1.f/(1.f + __expf(-x)); }
__device__ __forceinline__ float tanhf_(float x){
  float e = __expf(-2.f*fabsf(x));
  float t = (1.f - e)/(1.f + e);
  return x < 0.f ? -t : t;
}

// ---------------- setup kernels ----------------

__global__ void k_f32_to_f16(const float* __restrict__ s, f16* __restrict__ d, int n){
  int i = blockIdx.x*blockDim.x + threadIdx.x;
  if (i < n) d[i] = (f16)s[i];
}

// WA[dir][2048][832] = [ W_ih (300, zero-pad to 320) | W_hh (512) ], f16
__global__ void k_build_wa(const float* __restrict__ wihf, const float* __restrict__ whhf,
                           const float* __restrict__ wihr, const float* __restrict__ whhr,
                           f16* __restrict__ WA){
  int i = blockIdx.x*blockDim.x + threadIdx.x;
  if (i >= 2*G_*KA_) return;
  int d = i / (G_*KA_);
  int rem = i - d*(G_*KA_);
  int row = rem / KA_, k = rem - row*KA_;
  const float* wih = d ? wihr : wihf;
  const float* whh = d ? whhr : whhf;
  float v;
  if (k < 320) v = (k < E_) ? wih[(size_t)row*E_ + k] : 0.f;
  else         v = whh[(size_t)row*H_ + (k - 320)];
  WA[i] = (f16)v;
}

__global__ void k_bias(const float* __restrict__ a, const float* __restrict__ b,
                       float* __restrict__ d, int n){
  int i = blockIdx.x*blockDim.x + threadIdx.x;
  if (i < n) d[i] = a[i] + b[i];
}

__global__ void k_len(const float* __restrict__ x, int* __restrict__ len){
  int b = threadIdx.x;
  if (b < B_){
    int v = (int)x[((size_t)b*S_ + (S_-1))*E_];
    len[b] = v > S_ ? S_ : v;
  }
}

__global__ void k_init(f16* hstate, float* cstate){
  int i = blockIdx.x*blockDim.x + threadIdx.x;
  if (i < B_*H_){ hstate[i] = (f16)1.f; cstate[i] = 1.f; }
}

// ---------------- GEMM: C[M,N] = A[M,K] @ B[N,K]^T + bias (f16 in/out, fp32 acc) ----------------

__global__ __launch_bounds__(256) void k_gemm_bt(
    const f16* __restrict__ A, const f16* __restrict__ Bm,
    f16* __restrict__ C, const float* __restrict__ bias,
    int M, int N, int K)
{
  __shared__ f16 As[64*40];
  __shared__ f16 Bs[64*40];
  const int m0 = blockIdx.x*64, n0 = blockIdx.y*64;
  const int tid = threadIdx.x;
  const int w = tid>>6, lane = tid&63, quad = lane>>4, l16 = lane&15;
  const int wm = (w&1)*32, wn = (w>>1)*32;
  const int lr = tid>>2, lc = (tid&3)*8;
  const f16* Ap = A + (size_t)(m0+lr)*K + lc;
  const f16* Bp = Bm + (size_t)(n0+lr)*K + lc;
  f32x4 z4 = {0.f,0.f,0.f,0.f};
  f32x4 acc[2][2] = {{z4,z4},{z4,z4}};
  for (int k0 = 0; k0 < K; k0 += 32){
    *(uint4*)&As[lr*40+lc] = *(const uint4*)(Ap + k0);
    *(uint4*)&Bs[lr*40+lc] = *(const uint4*)(Bp + k0);
    __syncthreads();
    f16x8 a0 = *(const f16x8*)&As[(wm+l16)*40 + quad*8];
    f16x8 a1 = *(const f16x8*)&As[(wm+16+l16)*40 + quad*8];
    f16x8 b0 = *(const f16x8*)&Bs[(wn+l16)*40 + quad*8];
    f16x8 b1 = *(const f16x8*)&Bs[(wn+16+l16)*40 + quad*8];
    acc[0][0] = __builtin_amdgcn_mfma_f32_16x16x32_f16(a0,b0,acc[0][0],0,0,0);
    acc[0][1] = __builtin_amdgcn_mfma_f32_16x16x32_f16(a0,b1,acc[0][1],0,0,0);
    acc[1][0] = __builtin_amdgcn_mfma_f32_16x16x32_f16(a1,b0,acc[1][0],0,0,0);
    acc[1][1] = __builtin_amdgcn_mfma_f32_16x16x32_f16(a1,b1,acc[1][1],0,0,0);
    __syncthreads();
  }
#pragma unroll
  for (int mi = 0; mi < 2; ++mi)
#pragma unroll
    for (int ni = 0; ni < 2; ++ni){
      int col = n0 + wn + ni*16 + l16;
      float bz = bias[col];
#pragma unroll
      for (int r = 0; r < 4; ++r){
        int row = m0 + wm + mi*16 + quad*4 + r;
        C[(size_t)row*N + col] = (f16)(acc[mi][ni][r] + bz);
      }
    }
}

// ---------------- phase A: layer-0 fwd+rev, batch-partitioned (NO inter-block sync) ----------------
// 16 blocks x 1024 thr. Block = 16 batch rows x ALL 2048 gate cols, dir = bx&1
// (i%8 XCD round-robin pairs same-dir blocks -> shared 3.4MB W slice per XCD L2).
// A = [x_t | h] in LDS ([16][840] f16); B = WA streamed from L2; c in regs.
// h never leaves the block -> zero barriers/fences; 2 __syncthreads per step.

__global__ __launch_bounds__(1024, 1) void k_phaseA(
    const float* __restrict__ x, const f16* __restrict__ WA,
    const float* __restrict__ bs0, const int* __restrict__ len,
    f16* __restrict__ outcat)
{
  __shared__ f16 Ash[16*LDA_];
  const int bx = blockIdx.x;
  const int dir = bx & 1;
  const int m0 = (bx >> 1) * 16;
  const f16* W = WA + (size_t)dir*G_*KA_;
  const float* bias = bs0 + dir*G_;
  const int tid = threadIdx.x;
  const int w = tid >> 6, lane = tid & 63, quad = lane >> 4, l16 = lane & 15;
  const int jw = w*32;

  const f16* Wp[4][2];
  float bz[4][2];
#pragma unroll
  for (int g = 0; g < 4; ++g)
#pragma unroll
    for (int nt = 0; nt < 2; ++nt){
      int col = g*H_ + jw + nt*16 + l16;
      Wp[g][nt] = W + (size_t)col*KA_;
      bz[g][nt] = bias[col];
    }
  int lm[4];
#pragma unroll
  for (int r = 0; r < 4; ++r) lm[r] = len[m0 + quad*4 + r];
  float cpr[2][4];
#pragma unroll
  for (int nt = 0; nt < 2; ++nt)
#pragma unroll
    for (int r = 0; r < 4; ++r) cpr[nt][r] = 1.f;

  // h0 = 1
  for (int u = tid; u < 16*H_; u += 1024)
    Ash[(u>>9)*LDA_ + 320 + (u & 511)] = (f16)1.f;

  for (int s = 0; s < S_; ++s){
    const int t = dir ? (S_-1-s) : s;
    // stage x_t (f32 -> f16) into A[:, 0:320)
    for (int u = tid; u < 16*320; u += 1024){
      int m = u / 320, e = u - m*320;
      float v = (e < E_) ? x[((size_t)(m0+m)*S_ + t)*E_ + e] : 0.f;
      Ash[m*LDA_ + e] = (f16)v;
    }
    __syncthreads();   // x staged + prev h visible to all waves

    f32x4 z4 = {0.f,0.f,0.f,0.f};
    f32x4 acc[4][2] = {{z4,z4},{z4,z4},{z4,z4},{z4,z4}};
#pragma unroll
    for (int kb = 0; kb < 26; ++kb){
      f16x8 a = *(const f16x8*)&Ash[l16*LDA_ + kb*32 + quad*8];
#pragma unroll
      for (int g = 0; g < 4; ++g){
        acc[g][0] = __builtin_amdgcn_mfma_f32_16x16x32_f16(a, *(const f16x8*)(Wp[g][0] + kb*32 + quad*8), acc[g][0],0,0,0);
        acc[g][1] = __builtin_amdgcn_mfma_f32_16x16x32_f16(a, *(const f16x8*)(Wp[g][1] + kb*32 + quad*8), acc[g][1],0,0,0);
      }
    }
    __syncthreads();   // all A reads done before h overwrite

#pragma unroll
    for (int nt = 0; nt < 2; ++nt)
#pragma unroll
      for (int r = 0; r < 4; ++r){
        int m = quad*4 + r;
        int j = jw + nt*16 + l16;
        float zi = acc[0][nt][r] + bz[0][nt];
        float zf = acc[1][nt][r] + bz[1][nt];
        float zg = acc[2][nt][r] + bz[2][nt];
        float zo = acc[3][nt][r] + bz[3][nt];
        float ig = sigf(zi), fg = sigf(zf), gg = tanhf_(zg), og = sigf(zo);
        float cnew = fg*cpr[nt][r] + ig*gg;
        float hnew = og*tanhf_(cnew);
        bool mk = t < lm[r];
        float hprev = (float)Ash[m*LDA_ + 320 + j];
        float hsel = mk ? hnew : hprev;
        cpr[nt][r] = mk ? cnew : cpr[nt][r];
        Ash[m*LDA_ + 320 + j] = (f16)hsel;
        outcat[((size_t)t*B_ + m0 + m)*D1_ + dir*H_ + j] = (f16)hsel;
      }
    // next iter's x-stage + top __syncthreads provide the write->read barrier
  }
}

// ---------------- phase C: layer-1 reverse recurrence over a CH-step chunk ----------------
// 8 blocks x 1024 thr; Z1c (x-part, bias included) precomputed by k_gemm_bt.
// W_hh1 (2MB) streamed from L2; h in LDS; c in regs; state persisted via global.

__global__ __launch_bounds__(1024, 1) void k_phaseC(
    const f16* __restrict__ Z1c, const f16* __restrict__ w1h,
    const int* __restrict__ len,
    f16* __restrict__ hstate, float* __restrict__ cstate,
    float* __restrict__ h1f, int t0, int CH)
{
  __shared__ f16 Ash[16*LDC_];
  const int m0 = blockIdx.x * 16;
  const int tid = threadIdx.x;
  const int w = tid >> 6, lane = tid & 63, quad = lane >> 4, l16 = lane & 15;
  const int jw = w*32;

  const f16* Wp[4][2];
#pragma unroll
  for (int g = 0; g < 4; ++g)
#pragma unroll
    for (int nt = 0; nt < 2; ++nt)
      Wp[g][nt] = w1h + (size_t)(g*H_ + jw + nt*16 + l16)*H_;
  int lm[4];
#pragma unroll
  for (int r = 0; r < 4; ++r) lm[r] = len[m0 + quad*4 + r];
  float cpr[2][4];
#pragma unroll
  for (int nt = 0; nt < 2; ++nt)
#pragma unroll
    for (int r = 0; r < 4; ++r)
      cpr[nt][r] = cstate[(size_t)(m0 + quad*4 + r)*H_ + jw + nt*16 + l16];
  for (int u = tid; u < 16*H_; u += 1024)
    Ash[(u>>9)*LDC_ + (u & 511)] = hstate[(size_t)(m0 + (u>>9))*H_ + (u & 511)];
  __syncthreads();

  for (int sl = 0; sl < CH; ++sl){
    const int t = t0 + CH - 1 - sl;
    const int zrow = CH - 1 - sl;
    // prefetch Z rows (independent of h -> overlaps MFMA)
    float zv[4][2][4];
#pragma unroll
    for (int g = 0; g < 4; ++g)
#pragma unroll
      for (int nt = 0; nt < 2; ++nt)
#pragma unroll
        for (int r = 0; r < 4; ++r)
          zv[g][nt][r] = (float)Z1c[((size_t)zrow*B_ + m0 + quad*4 + r)*G_ + g*H_ + jw + nt*16 + l16];

    f32x4 z4 = {0.f,0.f,0.f,0.f};
    f32x4 acc[4][2] = {{z4,z4},{z4,z4},{z4,z4},{z4,z4}};
#pragma unroll
    for (int kb = 0; kb < 16; ++kb){
      f16x8 a = *(const f16x8*)&Ash[l16*LDC_ + kb*32 + quad*8];
#pragma unroll
      for (int g = 0; g < 4; ++g){
        acc[g][0] = __builtin_amdgcn_mfma_f32_16x16x32_f16(a, *(const f16x8*)(Wp[g][0] + kb*32 + quad*8), acc[g][0],0,0,0);
        acc[g][1] = __builtin_amdgcn_mfma_f32_16x16x32_f16(a, *(const f16x8*)(Wp[g][1] + kb*32 + quad*8), acc[g][1],0,0,0);
      }
    }
    __syncthreads();   // reads done

#pragma unroll
    for (int nt = 0; nt < 2; ++nt)
#pragma unroll
      for (int r = 0; r < 4; ++r){
        int m = quad*4 + r;
        int j = jw + nt*16 + l16;
        float zi = acc[0][nt][r] + zv[0][nt][r];
        float zf = acc[1][nt][r] + zv[1][nt][r];
        float zg = acc[2][nt][r] + zv[2][nt][r];
        float zo = acc[3][nt][r] + zv[3][nt][r];
        float ig = sigf(zi), fg = sigf(zf), gg = tanhf_(zg), og = sigf(zo);
        float cnew = fg*cpr[nt][r] + ig*gg;
        float hnew = og*tanhf_(cnew);
        bool mk = t < lm[r];
        float hprev = (float)Ash[m*LDC_ + j];
        float hsel = mk ? hnew : hprev;
        cpr[nt][r] = mk ? cnew : cpr[nt][r];
        Ash[m*LDC_ + j] = (f16)hsel;
        if (t == 0) h1f[(size_t)(m0+m)*H_ + j] = hsel;
      }
    __syncthreads();   // writes done before next step's reads
  }

  // persist state for next chunk launch
  for (int u = tid; u < 16*H_; u += 1024)
    hstate[(size_t)(m0 + (u>>9))*H_ + (u & 511)] = Ash[(u>>9)*LDC_ + (u & 511)];
#pragma unroll
  for (int nt = 0; nt < 2; ++nt)
#pragma unroll
    for (int r = 0; r < 4; ++r)
      cstate[(size_t)(m0 + quad*4 + r)*H_ + jw + nt*16 + l16] = cpr[nt][r];
}

// ---------------- epilogue: folded FC ----------------

__global__ void k_fold(const float* __restrict__ fc1w, const float* __restrict__ fc1b,
                       const float* __restrict__ fcw,  const float* __restrict__ fcb,
                       float* __restrict__ Mf, float* __restrict__ bf){
  int i = blockIdx.x*blockDim.x + threadIdx.x;
  if (i >= 1024) return;
  int o = i >> 9, h = i & 511;
  float s = 0.f;
  for (int jj = 0; jj < 512; ++jj) s += fcw[o*512 + jj] * fc1w[jj*512 + h];
  Mf[o*512 + h] = s;
  if (h == 0){
    float sb = fcb[o];
    for (int jj = 0; jj < 512; ++jj) sb += fcw[o*512 + jj] * fc1b[jj];
    bf[o] = sb;
  }
}

__global__ void k_final(const float* __restrict__ h1f, const float* __restrict__ Mf,
                        const float* __restrict__ bf, float* __restrict__ out){
  int i = threadIdx.x;
  if (i >= 256) return;
  int b = i >> 1, o = i & 1;
  float s = bf[o];
  const float* hp = h1f + (size_t)b*512;
  const float* mp = Mf + (size_t)o*512;
  for (int h = 0; h < 512; ++h) s += hp[h]*mp[h];
  out[b*2 + o] = s;
}

// ---------------- host ----------------

extern "C" void kernel_launch(void* const* d_in, const int* in_sizes, int n_in,
                              void* d_out, int out_size, void* d_ws, size_t ws_size,
                              hipStream_t stream)
{
  const float* x     = (const float*)d_in[0];
  const float* wih0f = (const float*)d_in[1];
  const float* whh0f = (const float*)d_in[2];
  const float* bih0f = (const float*)d_in[3];
  const float* bhh0f = (const float*)d_in[4];
  const float* wih0r = (const float*)d_in[5];
  const float* whh0r = (const float*)d_in[6];
  const float* bih0r = (const float*)d_in[7];
  const float* bhh0r = (const float*)d_in[8];
  // d_in[9..12] = layer1 forward: dead code (only hT_r of layer1 reaches output)
  const float* wih1r = (const float*)d_in[13];
  const float* whh1r = (const float*)d_in[14];
  const float* bih1r = (const float*)d_in[15];
  const float* bhh1r = (const float*)d_in[16];
  const float* fc1w  = (const float*)d_in[17];
  const float* fc1b  = (const float*)d_in[18];
  const float* fcw   = (const float*)d_in[19];
  const float* fcb   = (const float*)d_in[20];
  float* out = (float*)d_out;

  char* p = (char*)d_ws;
  auto alloc = [&](size_t bytes)->char*{
    char* r = p; p += (bytes + 255) & ~(size_t)255; return r;
  };
  f16* WA      = (f16*)alloc((size_t)2*G_*KA_*2);     // 6.8 MB
  f16* w1i     = (f16*)alloc((size_t)G_*D1_*2);       // 4 MB
  f16* w1h     = (f16*)alloc((size_t)G_*H_*2);        // 2 MB
  float* bs0   = (float*)alloc((size_t)2*G_*4);
  float* bs1r  = (float*)alloc(G_*4);
  int*   len   = (int*)alloc(B_*4);
  f16* outcat  = (f16*)alloc((size_t)S_*B_*D1_*2);    // 67 MB
  f16* hstate  = (f16*)alloc((size_t)B_*H_*2);
  float* cstate= (float*)alloc((size_t)B_*H_*4);
  float* h1f   = (float*)alloc((size_t)B_*H_*4);
  float* Mf    = (float*)alloc(2*512*4);
  float* bf    = (float*)alloc(256);
  // fixed ~81 MB; Z1c chunk adaptive:
  size_t used = (size_t)(p - (char*)d_ws);
  int CH = 8;
  for (int c = 64; c >= 8; c >>= 1){
    if (used + (size_t)c*B_*G_*2 <= ws_size){ CH = c; break; }
  }
  f16* Z1c = (f16*)alloc((size_t)CH*B_*G_*2);
  const int NC = S_/CH;

  int n;
  n = 2*G_*KA_; k_build_wa<<<(n+255)/256,256,0,stream>>>(wih0f, whh0f, wih0r, whh0r, WA);
  n = G_*D1_;   k_f32_to_f16<<<(n+255)/256,256,0,stream>>>(wih1r, w1i, n);
  n = G_*H_;    k_f32_to_f16<<<(n+255)/256,256,0,stream>>>(whh1r, w1h, n);
  k_bias<<<8,256,0,stream>>>(bih0f, bhh0f, bs0, G_);
  k_bias<<<8,256,0,stream>>>(bih0r, bhh0r, bs0 + G_, G_);
  k_bias<<<8,256,0,stream>>>(bih1r, bhh1r, bs1r, G_);
  k_len<<<1,128,0,stream>>>(x, len);
  n = B_*H_; k_init<<<(n+255)/256,256,0,stream>>>(hstate, cstate);
  k_fold<<<4,256,0,stream>>>(fc1w, fc1b, fcw, fcb, Mf, bf);

  // phase A: single persistent launch, no inter-block dependencies
  k_phaseA<<<16, 1024, 0, stream>>>(x, WA, bs0, len, outcat);

  // phase C: per chunk, Z1 GEMM (x-part+bias) then recurrence
  for (int cc = 0; cc < NC; ++cc){
    int t0 = S_ - (cc+1)*CH;
    k_gemm_bt<<<dim3(CH*2,32), 256, 0, stream>>>(outcat + (size_t)t0*B_*D1_, w1i, Z1c, bs1r, CH*B_, G_, D1_);
    k_phaseC<<<8, 1024, 0, stream>>>(Z1c, w1h, len, hstate, cstate, h1f, t0, CH);
  }

  k_final<<<1,256,0,stream>>>(h1f, Mf, bf, out);
}

// Round 6
// 7434.055 us; speedup vs baseline: 5.2806x; 5.2806x over previous
//
#include <hip/hip_runtime.h>

#define B_  128
#define S_  256
#define E_  300
#define EP_ 320
#define H_  512
#define G_  2048   // 4*H
#define D1_ 1024   // 2*H

typedef _Float16 f16;
typedef __attribute__((ext_vector_type(8))) _Float16 f16x8;
typedef __attribute__((ext_vector_type(4))) float    f32x4;
typedef unsigned long long u64;
typedef unsigned int u32;

__device__ __forceinline__ float sigf(float x){ return 1.f/(1.f + __expf(-x)); }
__device__ __forceinline__ float tanhf_(float x){
  float e = __expf(-2.f*fabsf(x));
  float t = (1.f - e)/(1.f + e);
  return x < 0.f ? -t : t;
}

// Relaxed agent-scope atomics: route to the coherence point (IF$), bypassing the
// non-coherent per-XCD L2s. NO acquire/release -> compiler never emits
// buffer_wbl2/inv -> L2 stays warm for the weight streams (round-4's poison).
__device__ __forceinline__ u64 aload64(const u64* p){
  return __hip_atomic_load((u64*)p, __ATOMIC_RELAXED, __HIP_MEMORY_SCOPE_AGENT);
}
__device__ __forceinline__ void astore32(u32* p, u32 v){
  __hip_atomic_store(p, v, __ATOMIC_RELAXED, __HIP_MEMORY_SCOPE_AGENT);
}
union H8 { u64 q[2]; f16x8 v; };
union FU { f16 f; unsigned short s; };

// ---------------- setup kernels ----------------

__global__ void k_f32_to_f16(const float* __restrict__ s, f16* __restrict__ d, int n){
  int i = blockIdx.x*blockDim.x + threadIdx.x;
  if (i < n) d[i] = (f16)s[i];
}

__global__ void k_pad_w(const float* __restrict__ s, f16* __restrict__ d, int rows, int ks, int kd){
  int i = blockIdx.x*blockDim.x + threadIdx.x;
  if (i >= rows*kd) return;
  int r = i/kd, k = i - r*kd;
  d[i] = (k < ks) ? (f16)s[(size_t)r*ks + k] : (f16)0.f;
}

__global__ void k_bias(const float* __restrict__ a, const float* __restrict__ b,
                       float* __restrict__ d, int n){
  int i = blockIdx.x*blockDim.x + threadIdx.x;
  if (i < n) d[i] = a[i] + b[i];
}

__global__ void k_len(const float* __restrict__ x, int* __restrict__ len){
  int b = threadIdx.x;
  if (b < B_){
    int v = (int)x[((size_t)b*S_ + (S_-1))*E_];
    len[b] = v > S_ ? S_ : v;
  }
}

// hxA: [dir][parity][B*H] f16, hx1: [parity][B*H]; parity-0 slots init to 1 (h0=c0=1).
// barA: 4 groups x S slots, barC: 2 x S. Runs every launch (ws re-poisoned).
__global__ void k_init(f16* hxA, f16* hx1, u32* barA, u32* barC){
  int i = blockIdx.x*blockDim.x + threadIdx.x;
  if (i < B_*H_){
    hxA[i] = (f16)1.f;                // dir0 par0
    hxA[2*B_*H_ + i] = (f16)1.f;      // dir1 par0
    hx1[i] = (f16)1.f;                // par0
  }
  if (i < 4*S_) barA[i] = 0u;
  if (i < 2*S_) barC[i] = 0u;
}

// ---------------- phase A: persistent layer-0 fwd+rev, column-partitioned ----------------
// grid (2,32,2) = 128 blocks, 256 thr. Block: 64 batch rows (half) x 16 hidden x 4 gates.
// W_hh slice in LDS (64KB, staged ONCE, xor-swizzled conflict-free); W_ih slice streamed
// from L2 (read-only, stays cached); h exchanged via IF$ relaxed atomics; per-step slot
// barrier per (dir,half) group of 32 blocks. c/h-prev in regs.

__global__ __launch_bounds__(256, 1) void k_phaseA(
    const float* __restrict__ x,
    const f16* __restrict__ w0f, const f16* __restrict__ w0r,
    const f16* __restrict__ whf, const f16* __restrict__ whr,
    const float* __restrict__ bs0, const int* __restrict__ len,
    f16* __restrict__ hxA, f16* __restrict__ outcat,
    u32* __restrict__ barA)
{
  __shared__ f16 Wh[64*512];   // exactly 64 KB
  const int half = blockIdx.x, jb = blockIdx.y, dir = blockIdx.z;
  const f16* wih = dir ? w0r : w0f;
  const f16* whh = dir ? whr : whf;
  const float* bias = bs0 + dir*G_;
  f16* hx = hxA + (size_t)dir*(2*B_*H_);
  u32* mybar = barA + (dir*2 + half)*S_;
  const int tid = threadIdx.x;
  const int w = tid>>6, lane = tid&63, quad = lane>>4, l16 = lane&15;
  const int j0 = jb*16;
  const int m0 = half*64 + w*16;       // this wave's 16 batch rows

  // stage W_hh slice once: 64 rows (4g x 16j) x 512 k; 16B unit u stored at u^(row&7)
  for (int u = tid; u < 4096; u += 256){
    int lrr = u>>6, uc = u&63;
    int g = lrr>>4, i = lrr&15;
    *(uint4*)&Wh[lrr*512 + (uc ^ (i&7))*8] =
        *(const uint4*)(whh + ((size_t)(g*H_ + j0 + i))*H_ + uc*8);
  }
  __syncthreads();

  const int j = j0 + l16;
  const f16* wiB[4];
#pragma unroll
  for (int g = 0; g < 4; ++g) wiB[g] = wih + (size_t)(g*H_ + j)*EP_ + quad*8;
  float bz[4], hprev[4], cpr[4]; int lm[4];
#pragma unroll
  for (int g = 0; g < 4; ++g) bz[g] = bias[g*H_ + j];
#pragma unroll
  for (int r = 0; r < 4; ++r){ hprev[r] = 1.f; cpr[r] = 1.f; lm[r] = len[m0 + quad*4 + r]; }
  const size_t xrowbase = (size_t)(m0 + l16)*S_;

  for (int s = 0; s < S_; ++s){
    const int t = dir ? (S_-1-s) : s;
    f32x4 z4 = {0.f,0.f,0.f,0.f};
    f32x4 acc[4] = {z4,z4,z4,z4};

    // --- x_t @ Wih^T (h-independent; overlaps the barrier wait) ---
    const float* xr = x + (xrowbase + t)*E_;
#pragma unroll
    for (int kb = 0; kb < 9; ++kb){
      float4 f0 = *(const float4*)(xr + kb*32 + quad*8);
      float4 f1 = *(const float4*)(xr + kb*32 + quad*8 + 4);
      f16x8 a;
      a[0]=(f16)f0.x; a[1]=(f16)f0.y; a[2]=(f16)f0.z; a[3]=(f16)f0.w;
      a[4]=(f16)f1.x; a[5]=(f16)f1.y; a[6]=(f16)f1.z; a[7]=(f16)f1.w;
#pragma unroll
      for (int g = 0; g < 4; ++g)
        acc[g] = __builtin_amdgcn_mfma_f32_16x16x32_f16(a, *(const f16x8*)(wiB[g] + kb*32), acc[g],0,0,0);
    }
    { // K tail 288..319 (x valid to 299; weight pad rows are zero)
      int kbase = 288 + quad*8;
      f16x8 a;
#pragma unroll
      for (int e2 = 0; e2 < 8; ++e2)
        a[e2] = (kbase + e2 < E_) ? (f16)xr[kbase + e2] : (f16)0.f;
#pragma unroll
      for (int g = 0; g < 4; ++g)
        acc[g] = __builtin_amdgcn_mfma_f32_16x16x32_f16(a, *(const f16x8*)(wiB[g] + 288), acc[g],0,0,0);
    }

    // --- wait for step s-1 of this (dir,half) group (32 producer blocks) ---
    if (s > 0){
      if (tid == 0){
        while (__hip_atomic_load(&mybar[s-1], __ATOMIC_RELAXED, __HIP_MEMORY_SCOPE_AGENT) < 32u) {}
      }
      __syncthreads();
    }

    // --- h @ Whh^T (K=512); A via IF$ atomic loads, B from LDS ---
    const int par = s & 1;
    const u64* hap = (const u64*)(hx + (size_t)par*(B_*H_) + (size_t)(m0 + l16)*H_);
#pragma unroll
    for (int kb = 0; kb < 16; ++kb){
      H8 ha;
      ha.q[0] = aload64(hap + kb*8 + quad*2);
      ha.q[1] = aload64(hap + kb*8 + quad*2 + 1);
      int uq = kb*4 + quad;
#pragma unroll
      for (int g = 0; g < 4; ++g){
        f16x8 b = *(const f16x8*)&Wh[(g*16+l16)*512 + ((uq ^ (l16&7)))*8];
        acc[g] = __builtin_amdgcn_mfma_f32_16x16x32_f16(ha.v, b, acc[g],0,0,0);
      }
    }

    // --- gates + state update; publish h via IF$ (packed 4B, even lanes) ---
    f16* hn = hx + (size_t)(1-par)*(B_*H_);
#pragma unroll
    for (int r = 0; r < 4; ++r){
      int m = m0 + quad*4 + r;
      float zi = acc[0][r] + bz[0];
      float zf = acc[1][r] + bz[1];
      float zg = acc[2][r] + bz[2];
      float zo = acc[3][r] + bz[3];
      float ig = sigf(zi), fg = sigf(zf), gg = tanhf_(zg), og = sigf(zo);
      float cnew = fg*cpr[r] + ig*gg;
      float hnew = og*tanhf_(cnew);
      bool mk = t < lm[r];
      float hsel = mk ? hnew : hprev[r];
      cpr[r] = mk ? cnew : cpr[r];
      hprev[r] = hsel;
      FU cv; cv.f = (f16)hsel;
      int other = __shfl_down((int)cv.s, 1);
      if ((l16 & 1) == 0){
        u32 packed = (u32)cv.s | ((u32)other << 16);
        astore32((u32*)(hn + (size_t)m*H_ + j), packed);
        *(u32*)(outcat + ((size_t)t*B_ + m)*D1_ + dir*H_ + j) = packed;  // plain; read after kernel end
      }
    }
    __syncthreads();   // compiler drains vmcnt(0) before s_barrier -> h stores at IF$
    if (tid == 0)
      __hip_atomic_fetch_add(&mybar[s], 1u, __ATOMIC_RELAXED, __HIP_MEMORY_SCOPE_AGENT);
  }
}

// ---------------- phase C: persistent layer-1 reverse, column-partitioned ----------------
// grid (2,32,1) = 64 blocks. W_hh1 slice in LDS (64KB); W1_ih slice (128KB) + outcat
// A-rows streamed from L2 (both h-independent -> overlap barrier). Fuses the layer-1
// input GEMM (no separate k_gemm_bt). Groups of 32 blocks per batch-half.

__global__ __launch_bounds__(256, 1) void k_phaseC(
    const f16* __restrict__ outcat, const f16* __restrict__ w1i,
    const f16* __restrict__ w1h, const float* __restrict__ bs1r,
    const int* __restrict__ len,
    f16* __restrict__ hx1, float* __restrict__ h1f,
    u32* __restrict__ barC)
{
  __shared__ f16 Wh[64*512];   // 64 KB
  const int half = blockIdx.x, jb = blockIdx.y;
  u32* mybar = barC + half*S_;
  const int tid = threadIdx.x;
  const int w = tid>>6, lane = tid&63, quad = lane>>4, l16 = lane&15;
  const int j0 = jb*16;
  const int m0 = half*64 + w*16;

  for (int u = tid; u < 4096; u += 256){
    int lrr = u>>6, uc = u&63;
    int g = lrr>>4, i = lrr&15;
    *(uint4*)&Wh[lrr*512 + (uc ^ (i&7))*8] =
        *(const uint4*)(w1h + ((size_t)(g*H_ + j0 + i))*H_ + uc*8);
  }
  __syncthreads();

  const int j = j0 + l16;
  const f16* wiB[4];
#pragma unroll
  for (int g = 0; g < 4; ++g) wiB[g] = w1i + (size_t)(g*H_ + j)*D1_ + quad*8;
  float bz[4], hprev[4], cpr[4]; int lm[4];
#pragma unroll
  for (int g = 0; g < 4; ++g) bz[g] = bs1r[g*H_ + j];
#pragma unroll
  for (int r = 0; r < 4; ++r){ hprev[r] = 1.f; cpr[r] = 1.f; lm[r] = len[m0 + quad*4 + r]; }

  for (int s = 0; s < S_; ++s){
    const int t = S_-1-s;
    f32x4 z4 = {0.f,0.f,0.f,0.f};
    f32x4 acc[4] = {z4,z4,z4,z4};

    // --- outcat_t @ W1ih^T (K=1024, h-independent) ---
    const f16* arow = outcat + ((size_t)t*B_ + m0 + l16)*D1_ + quad*8;
#pragma unroll
    for (int kb = 0; kb < 32; ++kb){
      f16x8 a = *(const f16x8*)(arow + kb*32);
#pragma unroll
      for (int g = 0; g < 4; ++g)
        acc[g] = __builtin_amdgcn_mfma_f32_16x16x32_f16(a, *(const f16x8*)(wiB[g] + kb*32), acc[g],0,0,0);
    }

    if (s > 0){
      if (tid == 0){
        while (__hip_atomic_load(&mybar[s-1], __ATOMIC_RELAXED, __HIP_MEMORY_SCOPE_AGENT) < 32u) {}
      }
      __syncthreads();
    }

    // --- h @ Whh1^T (K=512) ---
    const int par = s & 1;
    const u64* hap = (const u64*)(hx1 + (size_t)par*(B_*H_) + (size_t)(m0 + l16)*H_);
#pragma unroll
    for (int kb = 0; kb < 16; ++kb){
      H8 ha;
      ha.q[0] = aload64(hap + kb*8 + quad*2);
      ha.q[1] = aload64(hap + kb*8 + quad*2 + 1);
      int uq = kb*4 + quad;
#pragma unroll
      for (int g = 0; g < 4; ++g){
        f16x8 b = *(const f16x8*)&Wh[(g*16+l16)*512 + ((uq ^ (l16&7)))*8];
        acc[g] = __builtin_amdgcn_mfma_f32_16x16x32_f16(ha.v, b, acc[g],0,0,0);
      }
    }

    f16* hn = hx1 + (size_t)(1-par)*(B_*H_);
#pragma unroll
    for (int r = 0; r < 4; ++r){
      int m = m0 + quad*4 + r;
      float zi = acc[0][r] + bz[0];
      float zf = acc[1][r] + bz[1];
      float zg = acc[2][r] + bz[2];
      float zo = acc[3][r] + bz[3];
      float ig = sigf(zi), fg = sigf(zf), gg = tanhf_(zg), og = sigf(zo);
      float cnew = fg*cpr[r] + ig*gg;
      float hnew = og*tanhf_(cnew);
      bool mk = t < lm[r];
      float hsel = mk ? hnew : hprev[r];
      cpr[r] = mk ? cnew : cpr[r];
      hprev[r] = hsel;
      FU cv; cv.f = (f16)hsel;
      int other = __shfl_down((int)cv.s, 1);
      if ((l16 & 1) == 0){
        u32 packed = (u32)cv.s | ((u32)other << 16);
        astore32((u32*)(hn + (size_t)m*H_ + j), packed);
      }
      if (t == 0) h1f[(size_t)m*H_ + j] = hsel;   // final state (plain; read next kernel)
    }
    __syncthreads();
    if (tid == 0)
      __hip_atomic_fetch_add(&mybar[s], 1u, __ATOMIC_RELAXED, __HIP_MEMORY_SCOPE_AGENT);
  }
}

// ---------------- epilogue: folded FC ----------------

__global__ void k_fold(const float* __restrict__ fc1w, const float* __restrict__ fc1b,
                       const float* __restrict__ fcw,  const float* __restrict__ fcb,
                       float* __restrict__ Mf, float* __restrict__ bf){
  int i = blockIdx.x*blockDim.x + threadIdx.x;
  if (i >= 1024) return;
  int o = i >> 9, h = i & 511;
  float s = 0.f;
  for (int jj = 0; jj < 512; ++jj) s += fcw[o*512 + jj] * fc1w[jj*512 + h];
  Mf[o*512 + h] = s;
  if (h == 0){
    float sb = fcb[o];
    for (int jj = 0; jj < 512; ++jj) sb += fcw[o*512 + jj] * fc1b[jj];
    bf[o] = sb;
  }
}

__global__ void k_final(const float* __restrict__ h1f, const float* __restrict__ Mf,
                        const float* __restrict__ bf, float* __restrict__ out){
  int i = threadIdx.x;
  if (i >= 256) return;
  int b = i >> 1, o = i & 1;
  float s = bf[o];
  const float* hp = h1f + (size_t)b*512;
  const float* mp = Mf + (size_t)o*512;
  for (int h = 0; h < 512; ++h) s += hp[h]*mp[h];
  out[b*2 + o] = s;
}

// ---------------- host ----------------

extern "C" void kernel_launch(void* const* d_in, const int* in_sizes, int n_in,
                              void* d_out, int out_size, void* d_ws, size_t ws_size,
                              hipStream_t stream)
{
  const float* x     = (const float*)d_in[0];
  const float* wih0f = (const float*)d_in[1];
  const float* whh0f = (const float*)d_in[2];
  const float* bih0f = (const float*)d_in[3];
  const float* bhh0f = (const float*)d_in[4];
  const float* wih0r = (const float*)d_in[5];
  const float* whh0r = (const float*)d_in[6];
  const float* bih0r = (const float*)d_in[7];
  const float* bhh0r = (const float*)d_in[8];
  // d_in[9..12] = layer1 forward: dead code (only hT_r of layer1 reaches output)
  const float* wih1r = (const float*)d_in[13];
  const float* whh1r = (const float*)d_in[14];
  const float* bih1r = (const float*)d_in[15];
  const float* bhh1r = (const float*)d_in[16];
  const float* fc1w  = (const float*)d_in[17];
  const float* fc1b  = (const float*)d_in[18];
  const float* fcw   = (const float*)d_in[19];
  const float* fcb   = (const float*)d_in[20];
  float* out = (float*)d_out;

  char* p = (char*)d_ws;
  auto alloc = [&](size_t bytes)->char*{
    char* r = p; p += (bytes + 255) & ~(size_t)255; return r;
  };
  f16* w0fp   = (f16*)alloc((size_t)G_*EP_*2);       // 1.3 MB
  f16* w0rp   = (f16*)alloc((size_t)G_*EP_*2);
  f16* whf    = (f16*)alloc((size_t)G_*H_*2);        // 2 MB
  f16* whr    = (f16*)alloc((size_t)G_*H_*2);
  f16* w1i    = (f16*)alloc((size_t)G_*D1_*2);       // 4 MB
  f16* w1h    = (f16*)alloc((size_t)G_*H_*2);        // 2 MB
  float* bs0  = (float*)alloc((size_t)2*G_*4);
  float* bs1r = (float*)alloc(G_*4);
  int*   len  = (int*)alloc(B_*4);
  f16* outcat = (f16*)alloc((size_t)S_*B_*D1_*2);    // 67 MB
  f16* hxA    = (f16*)alloc((size_t)2*2*B_*H_*2);    // 512 KB
  f16* hx1    = (f16*)alloc((size_t)2*B_*H_*2);      // 256 KB
  float* h1f  = (float*)alloc((size_t)B_*H_*4);
  float* Mf   = (float*)alloc(2*512*4);
  float* bf   = (float*)alloc(256);
  u32* barA   = (u32*)alloc(4*S_*4);
  u32* barC   = (u32*)alloc(2*S_*4);
  // total ~81 MB (round 2 proved >= ~92 MB available)

  int n;
  n = G_*EP_; k_pad_w<<<(n+255)/256, 256, 0, stream>>>(wih0f, w0fp, G_, E_, EP_);
              k_pad_w<<<(n+255)/256, 256, 0, stream>>>(wih0r, w0rp, G_, E_, EP_);
  n = G_*H_;  k_f32_to_f16<<<(n+255)/256,256,0,stream>>>(whh0f, whf, n);
              k_f32_to_f16<<<(n+255)/256,256,0,stream>>>(whh0r, whr, n);
              k_f32_to_f16<<<(n+255)/256,256,0,stream>>>(whh1r, w1h, n);
  n = G_*D1_; k_f32_to_f16<<<(n+255)/256,256,0,stream>>>(wih1r, w1i, n);
  k_bias<<<8,256,0,stream>>>(bih0f, bhh0f, bs0, G_);
  k_bias<<<8,256,0,stream>>>(bih0r, bhh0r, bs0 + G_, G_);
  k_bias<<<8,256,0,stream>>>(bih1r, bhh1r, bs1r, G_);
  k_len<<<1,128,0,stream>>>(x, len);
  k_init<<<(B_*H_+255)/256,256,0,stream>>>(hxA, hx1, barA, barC);
  k_fold<<<4,256,0,stream>>>(fc1w, fc1b, fcw, fcb, Mf, bf);

  k_phaseA<<<dim3(2,32,2), 256, 0, stream>>>(
      x, w0fp, w0rp, whf, whr, bs0, len, hxA, outcat, barA);

  k_phaseC<<<dim3(2,32,1), 256, 0, stream>>>(
      outcat, w1i, w1h, bs1r, len, hx1, h1f, barC);

  k_final<<<1,256,0,stream>>>(h1f, Mf, bf, out);
}

// Round 7
// 4982.840 us; speedup vs baseline: 7.8782x; 1.4919x over previous
//
#include <hip/hip_runtime.h>

#define B_  128
#define S_  256
#define E_  300
#define EP_ 320
#define H_  512
#define G_  2048   // 4*H
#define D1_ 1024   // 2*H

typedef _Float16 f16;
typedef __attribute__((ext_vector_type(8))) _Float16 f16x8;
typedef __attribute__((ext_vector_type(4))) float    f32x4;
typedef unsigned long long u64;
typedef unsigned int u32;

__device__ __forceinline__ float sigf(float x){ return 1.f/(1.f + __expf(-x)); }
__device__ __forceinline__ float tanhf_(float x){
  float e = __expf(-2.f*fabsf(x));
  float t = (1.f - e)/(1.f + e);
  return x < 0.f ? -t : t;
}

// Relaxed agent-scope atomics: route to the coherence point (IF$), bypassing the
// non-coherent per-XCD L2s; no acquire/release -> no buffer_wbl2/inv -> L2 stays
// warm for the weight streams (round-4 lesson; round-6 validated).
__device__ __forceinline__ u64 aload64(const u64* p){
  return __hip_atomic_load((u64*)p, __ATOMIC_RELAXED, __HIP_MEMORY_SCOPE_AGENT);
}
__device__ __forceinline__ void astore32(u32* p, u32 v){
  __hip_atomic_store(p, v, __ATOMIC_RELAXED, __HIP_MEMORY_SCOPE_AGENT);
}
union H8 { u64 q[2]; f16x8 v; };
union FU { f16 f; unsigned short s; };

// ---------------- setup kernels ----------------

__global__ void k_f32_to_f16(const float* __restrict__ s, f16* __restrict__ d, int n){
  int i = blockIdx.x*blockDim.x + threadIdx.x;
  if (i < n) d[i] = (f16)s[i];
}

__global__ void k_pad_w(const float* __restrict__ s, f16* __restrict__ d, int rows, int ks, int kd){
  int i = blockIdx.x*blockDim.x + threadIdx.x;
  if (i >= rows*kd) return;
  int r = i/kd, k = i - r*kd;
  d[i] = (k < ks) ? (f16)s[(size_t)r*ks + k] : (f16)0.f;
}

__global__ void k_bias(const float* __restrict__ a, const float* __restrict__ b,
                       float* __restrict__ d, int n){
  int i = blockIdx.x*blockDim.x + threadIdx.x;
  if (i < n) d[i] = a[i] + b[i];
}

__global__ void k_len(const float* __restrict__ x, int* __restrict__ len){
  int b = threadIdx.x;
  if (b < B_){
    int v = (int)x[((size_t)b*S_ + (S_-1))*E_];
    len[b] = v > S_ ? S_ : v;
  }
}

// hxA: [dir][parity][B*H], hx1: [parity][B*H]; parity-0 = h0 = 1. cstate = c0 = 1.
__global__ void k_init(f16* hxA, f16* hx1, float* cstate, u32* barA, u32* barC){
  int i = blockIdx.x*blockDim.x + threadIdx.x;
  if (i < B_*H_){
    hxA[i] = (f16)1.f;                // dir0 par0
    hxA[2*B_*H_ + i] = (f16)1.f;      // dir1 par0
    hx1[i] = (f16)1.f;                // par0
    cstate[i] = 1.f;
  }
  if (i < 4*S_) barA[i] = 0u;
  if (i < 2*S_) barC[i] = 0u;
}

// ---------------- GEMM: C[M,N] = A[M,K] @ B[N,K]^T + bias (f16 in/out, fp32 acc) ----------------

__global__ __launch_bounds__(256) void k_gemm_bt(
    const f16* __restrict__ A, const f16* __restrict__ Bm,
    f16* __restrict__ C, const float* __restrict__ bias,
    int M, int N, int K)
{
  __shared__ f16 As[64*40];
  __shared__ f16 Bs[64*40];
  const int m0 = blockIdx.x*64, n0 = blockIdx.y*64;
  const int tid = threadIdx.x;
  const int w = tid>>6, lane = tid&63, quad = lane>>4, l16 = lane&15;
  const int wm = (w&1)*32, wn = (w>>1)*32;
  const int lr = tid>>2, lc = (tid&3)*8;
  const f16* Ap = A + (size_t)(m0+lr)*K + lc;
  const f16* Bp = Bm + (size_t)(n0+lr)*K + lc;
  f32x4 z4 = {0.f,0.f,0.f,0.f};
  f32x4 acc[2][2] = {{z4,z4},{z4,z4}};
  for (int k0 = 0; k0 < K; k0 += 32){
    *(uint4*)&As[lr*40+lc] = *(const uint4*)(Ap + k0);
    *(uint4*)&Bs[lr*40+lc] = *(const uint4*)(Bp + k0);
    __syncthreads();
    f16x8 a0 = *(const f16x8*)&As[(wm+l16)*40 + quad*8];
    f16x8 a1 = *(const f16x8*)&As[(wm+16+l16)*40 + quad*8];
    f16x8 b0 = *(const f16x8*)&Bs[(wn+l16)*40 + quad*8];
    f16x8 b1 = *(const f16x8*)&Bs[(wn+16+l16)*40 + quad*8];
    acc[0][0] = __builtin_amdgcn_mfma_f32_16x16x32_f16(a0,b0,acc[0][0],0,0,0);
    acc[0][1] = __builtin_amdgcn_mfma_f32_16x16x32_f16(a0,b1,acc[0][1],0,0,0);
    acc[1][0] = __builtin_amdgcn_mfma_f32_16x16x32_f16(a1,b0,acc[1][0],0,0,0);
    acc[1][1] = __builtin_amdgcn_mfma_f32_16x16x32_f16(a1,b1,acc[1][1],0,0,0);
    __syncthreads();
  }
#pragma unroll
  for (int mi = 0; mi < 2; ++mi)
#pragma unroll
    for (int ni = 0; ni < 2; ++ni){
      int col = n0 + wn + ni*16 + l16;
      float bz = bias[col];
#pragma unroll
      for (int r = 0; r < 4; ++r){
        int row = m0 + wm + mi*16 + quad*4 + r;
        C[(size_t)row*N + col] = (f16)(acc[mi][ni][r] + bz);
      }
    }
}

// ---------------- phase A: persistent layer-0 fwd+rev, column-partitioned ----------------
// grid (2,32,2) = 128 blocks, 256 thr. Block: 64 batch rows x 16 hidden x 4 gates.
// W_hh slice in LDS (64KB staged once); W_ih slice streamed from L2; h exchanged
// via IF$ relaxed atomics; per-step slot flag per (dir,half) group of 32 blocks.
// Critical-path order: x-GEMM (wait shadow) -> uniform wave poll -> h-GEMM ->
// gates -> h astore -> syncthreads(drain) -> flag -> deferred outcat stores.

__global__ __launch_bounds__(256, 1) void k_phaseA(
    const float* __restrict__ x,
    const f16* __restrict__ w0f, const f16* __restrict__ w0r,
    const f16* __restrict__ whf, const f16* __restrict__ whr,
    const float* __restrict__ bs0, const int* __restrict__ len,
    f16* __restrict__ hxA, f16* __restrict__ outcat,
    u32* __restrict__ barA)
{
  __shared__ f16 Wh[64*512];   // exactly 64 KB
  const int half = blockIdx.x, jb = blockIdx.y, dir = blockIdx.z;
  const f16* wih = dir ? w0r : w0f;
  const f16* whh = dir ? whr : whf;
  const float* bias = bs0 + dir*G_;
  f16* hx = hxA + (size_t)dir*(2*B_*H_);
  u32* mybar = barA + (dir*2 + half)*S_;
  const int tid = threadIdx.x;
  const int w = tid>>6, lane = tid&63, quad = lane>>4, l16 = lane&15;
  const int j0 = jb*16;
  const int m0 = half*64 + w*16;       // this wave's 16 batch rows

  for (int u = tid; u < 4096; u += 256){
    int lrr = u>>6, uc = u&63;
    int g = lrr>>4, i = lrr&15;
    *(uint4*)&Wh[lrr*512 + (uc ^ (i&7))*8] =
        *(const uint4*)(whh + ((size_t)(g*H_ + j0 + i))*H_ + uc*8);
  }
  __syncthreads();

  const int j = j0 + l16;
  const f16* wiB[4];
#pragma unroll
  for (int g = 0; g < 4; ++g) wiB[g] = wih + (size_t)(g*H_ + j)*EP_ + quad*8;
  float bz[4], hprev[4], cpr[4]; int lm[4];
#pragma unroll
  for (int g = 0; g < 4; ++g) bz[g] = bias[g*H_ + j];
#pragma unroll
  for (int r = 0; r < 4; ++r){ hprev[r] = 1.f; cpr[r] = 1.f; lm[r] = len[m0 + quad*4 + r]; }
  const size_t xrowbase = (size_t)(m0 + l16)*S_;

  for (int s = 0; s < S_; ++s){
    const int t = dir ? (S_-1-s) : s;
    f32x4 z4 = {0.f,0.f,0.f,0.f};
    f32x4 acc[4] = {z4,z4,z4,z4};

    // --- x_t @ Wih^T (h-independent; overlaps the barrier wait) ---
    const float* xr = x + (xrowbase + t)*E_;
#pragma unroll
    for (int kb = 0; kb < 9; ++kb){
      float4 f0 = *(const float4*)(xr + kb*32 + quad*8);
      float4 f1 = *(const float4*)(xr + kb*32 + quad*8 + 4);
      f16x8 a;
      a[0]=(f16)f0.x; a[1]=(f16)f0.y; a[2]=(f16)f0.z; a[3]=(f16)f0.w;
      a[4]=(f16)f1.x; a[5]=(f16)f1.y; a[6]=(f16)f1.z; a[7]=(f16)f1.w;
#pragma unroll
      for (int g = 0; g < 4; ++g)
        acc[g] = __builtin_amdgcn_mfma_f32_16x16x32_f16(a, *(const f16x8*)(wiB[g] + kb*32), acc[g],0,0,0);
    }
    { // K tail 288..319 (x valid to 299; weight pad cols are zero)
      int kbase = 288 + quad*8;
      f16x8 a;
#pragma unroll
      for (int e2 = 0; e2 < 8; ++e2)
        a[e2] = (kbase + e2 < E_) ? (f16)xr[kbase + e2] : (f16)0.f;
#pragma unroll
      for (int g = 0; g < 4; ++g)
        acc[g] = __builtin_amdgcn_mfma_f32_16x16x32_f16(a, *(const f16x8*)(wiB[g] + 288), acc[g],0,0,0);
    }

    // --- uniform per-wave poll (one broadcast load; waves proceed independently) ---
    if (s > 0){
      while (__hip_atomic_load(&mybar[s-1], __ATOMIC_RELAXED, __HIP_MEMORY_SCOPE_AGENT) < 32u) {}
    }

    // --- h @ Whh^T (K=512); A via IF$ atomic loads, B from LDS ---
    const int par = s & 1;
    const u64* hap = (const u64*)(hx + (size_t)par*(B_*H_) + (size_t)(m0 + l16)*H_);
#pragma unroll
    for (int kb = 0; kb < 16; ++kb){
      H8 ha;
      ha.q[0] = aload64(hap + kb*8 + quad*2);
      ha.q[1] = aload64(hap + kb*8 + quad*2 + 1);
      int uq = kb*4 + quad;
#pragma unroll
      for (int g = 0; g < 4; ++g){
        f16x8 b = *(const f16x8*)&Wh[(g*16+l16)*512 + ((uq ^ (l16&7)))*8];
        acc[g] = __builtin_amdgcn_mfma_f32_16x16x32_f16(ha.v, b, acc[g],0,0,0);
      }
    }

    // --- gates + state update; publish h via IF$ (packed 4B, even lanes) ---
    f16* hn = hx + (size_t)(1-par)*(B_*H_);
#pragma unroll
    for (int r = 0; r < 4; ++r){
      int m = m0 + quad*4 + r;
      float zi = acc[0][r] + bz[0];
      float zf = acc[1][r] + bz[1];
      float zg = acc[2][r] + bz[2];
      float zo = acc[3][r] + bz[3];
      float ig = sigf(zi), fg = sigf(zf), gg = tanhf_(zg), og = sigf(zo);
      float cnew = fg*cpr[r] + ig*gg;
      float hnew = og*tanhf_(cnew);
      bool mk = t < lm[r];
      float hsel = mk ? hnew : hprev[r];
      cpr[r] = mk ? cnew : cpr[r];
      hprev[r] = hsel;
      FU cv; cv.f = (f16)hsel;
      int other = __shfl_down((int)cv.s, 1);
      if ((l16 & 1) == 0)
        astore32((u32*)(hn + (size_t)m*H_ + j), (u32)cv.s | ((u32)other << 16));
    }
    __syncthreads();   // drains h atomic stores (vmcnt(0) before s_barrier)
    if (tid == 0)
      __hip_atomic_fetch_add(&mybar[s], 1u, __ATOMIC_RELAXED, __HIP_MEMORY_SCOPE_AGENT);

    // --- deferred outcat stores (off the inter-block critical path) ---
#pragma unroll
    for (int r = 0; r < 4; ++r){
      int m = m0 + quad*4 + r;
      FU cv; cv.f = (f16)hprev[r];
      int other = __shfl_down((int)cv.s, 1);
      if ((l16 & 1) == 0)
        *(u32*)(outcat + ((size_t)t*B_ + m)*D1_ + dir*H_ + j) = (u32)cv.s | ((u32)other << 16);
    }
  }
}

// ---------------- phase C recurrence: layer-1 reverse over one CH-step chunk ----------------
// grid (2,32) = 64 blocks. Z1c (x-part + bias) precomputed by dense GEMM -> this
// kernel is only the K=512 h-GEMM + gates. W_hh1 slice in LDS; Z prefetched to
// regs before the wait; c persisted in cstate across chunk launches.

__global__ __launch_bounds__(256, 1) void k_phaseCrec(
    const f16* __restrict__ Z1c, const f16* __restrict__ w1h,
    const int* __restrict__ len,
    f16* __restrict__ hx1, float* __restrict__ cstate, float* __restrict__ h1f,
    u32* __restrict__ barC, int s0, int CH)
{
  __shared__ f16 Wh[64*512];   // 64 KB
  const int half = blockIdx.x, jb = blockIdx.y;
  u32* mybar = barC + half*S_;
  const int tid = threadIdx.x;
  const int w = tid>>6, lane = tid&63, quad = lane>>4, l16 = lane&15;
  const int j0 = jb*16;
  const int m0 = half*64 + w*16;

  for (int u = tid; u < 4096; u += 256){
    int lrr = u>>6, uc = u&63;
    int g = lrr>>4, i = lrr&15;
    *(uint4*)&Wh[lrr*512 + (uc ^ (i&7))*8] =
        *(const uint4*)(w1h + ((size_t)(g*H_ + j0 + i))*H_ + uc*8);
  }
  __syncthreads();

  const int j = j0 + l16;
  float hprev[4], cpr[4]; int lm[4];
#pragma unroll
  for (int r = 0; r < 4; ++r){
    int m = m0 + quad*4 + r;
    lm[r] = len[m];
    cpr[r] = cstate[(size_t)m*H_ + j];
    hprev[r] = (float)hx1[(size_t)(s0 & 1)*(B_*H_) + (size_t)m*H_ + j];
  }

  for (int sl = 0; sl < CH; ++sl){
    const int s = s0 + sl;
    const int t = S_-1-s;
    const int zrow = CH-1-sl;

    // --- prefetch Z rows (h-independent; overlaps the wait) ---
    float zv[4][4];
#pragma unroll
    for (int g = 0; g < 4; ++g)
#pragma unroll
      for (int r = 0; r < 4; ++r)
        zv[g][r] = (float)Z1c[((size_t)zrow*B_ + m0 + quad*4 + r)*G_ + g*H_ + j];

    if (s > 0){
      while (__hip_atomic_load(&mybar[s-1], __ATOMIC_RELAXED, __HIP_MEMORY_SCOPE_AGENT) < 32u) {}
    }

    // --- h @ Whh1^T (K=512) ---
    const int par = s & 1;
    const u64* hap = (const u64*)(hx1 + (size_t)par*(B_*H_) + (size_t)(m0 + l16)*H_);
    f32x4 z4 = {0.f,0.f,0.f,0.f};
    f32x4 acc[4] = {z4,z4,z4,z4};
#pragma unroll
    for (int kb = 0; kb < 16; ++kb){
      H8 ha;
      ha.q[0] = aload64(hap + kb*8 + quad*2);
      ha.q[1] = aload64(hap + kb*8 + quad*2 + 1);
      int uq = kb*4 + quad;
#pragma unroll
      for (int g = 0; g < 4; ++g){
        f16x8 b = *(const f16x8*)&Wh[(g*16+l16)*512 + ((uq ^ (l16&7)))*8];
        acc[g] = __builtin_amdgcn_mfma_f32_16x16x32_f16(ha.v, b, acc[g],0,0,0);
      }
    }

    f16* hn = hx1 + (size_t)(1-par)*(B_*H_);
#pragma unroll
    for (int r = 0; r < 4; ++r){
      int m = m0 + quad*4 + r;
      float zi = acc[0][r] + zv[0][r];
      float zf = acc[1][r] + zv[1][r];
      float zg = acc[2][r] + zv[2][r];
      float zo = acc[3][r] + zv[3][r];
      float ig = sigf(zi), fg = sigf(zf), gg = tanhf_(zg), og = sigf(zo);
      float cnew = fg*cpr[r] + ig*gg;
      float hnew = og*tanhf_(cnew);
      bool mk = t < lm[r];
      float hsel = mk ? hnew : hprev[r];
      cpr[r] = mk ? cnew : cpr[r];
      hprev[r] = hsel;
      FU cv; cv.f = (f16)hsel;
      int other = __shfl_down((int)cv.s, 1);
      if ((l16 & 1) == 0)
        astore32((u32*)(hn + (size_t)m*H_ + j), (u32)cv.s | ((u32)other << 16));
    }
    __syncthreads();
    if (tid == 0)
      __hip_atomic_fetch_add(&mybar[s], 1u, __ATOMIC_RELAXED, __HIP_MEMORY_SCOPE_AGENT);

    if (t == 0){  // deferred final-state write (consumed by k_final after kernel end)
#pragma unroll
      for (int r = 0; r < 4; ++r)
        h1f[(size_t)(m0 + quad*4 + r)*H_ + j] = hprev[r];
    }
  }

  // persist c across chunk launches (h lives in hx1 parity buffers)
#pragma unroll
  for (int r = 0; r < 4; ++r)
    cstate[(size_t)(m0 + quad*4 + r)*H_ + j] = cpr[r];
}

// ---------------- epilogue: folded FC ----------------

__global__ void k_fold(const float* __restrict__ fc1w, const float* __restrict__ fc1b,
                       const float* __restrict__ fcw,  const float* __restrict__ fcb,
                       float* __restrict__ Mf, float* __restrict__ bf){
  int i = blockIdx.x*blockDim.x + threadIdx.x;
  if (i >= 1024) return;
  int o = i >> 9, h = i & 511;
  float s = 0.f;
  for (int jj = 0; jj < 512; ++jj) s += fcw[o*512 + jj] * fc1w[jj*512 + h];
  Mf[o*512 + h] = s;
  if (h == 0){
    float sb = fcb[o];
    for (int jj = 0; jj < 512; ++jj) sb += fcw[o*512 + jj] * fc1b[jj];
    bf[o] = sb;
  }
}

__global__ void k_final(const float* __restrict__ h1f, const float* __restrict__ Mf,
                        const float* __restrict__ bf, float* __restrict__ out){
  int i = threadIdx.x;
  if (i >= 256) return;
  int b = i >> 1, o = i & 1;
  float s = bf[o];
  const float* hp = h1f + (size_t)b*512;
  const float* mp = Mf + (size_t)o*512;
  for (int h = 0; h < 512; ++h) s += hp[h]*mp[h];
  out[b*2 + o] = s;
}

// ---------------- host ----------------

extern "C" void kernel_launch(void* const* d_in, const int* in_sizes, int n_in,
                              void* d_out, int out_size, void* d_ws, size_t ws_size,
                              hipStream_t stream)
{
  const float* x     = (const float*)d_in[0];
  const float* wih0f = (const float*)d_in[1];
  const float* whh0f = (const float*)d_in[2];
  const float* bih0f = (const float*)d_in[3];
  const float* bhh0f = (const float*)d_in[4];
  const float* wih0r = (const float*)d_in[5];
  const float* whh0r = (const float*)d_in[6];
  const float* bih0r = (const float*)d_in[7];
  const float* bhh0r = (const float*)d_in[8];
  // d_in[9..12] = layer1 forward: dead code (only hT_r of layer1 reaches output)
  const float* wih1r = (const float*)d_in[13];
  const float* whh1r = (const float*)d_in[14];
  const float* bih1r = (const float*)d_in[15];
  const float* bhh1r = (const float*)d_in[16];
  const float* fc1w  = (const float*)d_in[17];
  const float* fc1b  = (const float*)d_in[18];
  const float* fcw   = (const float*)d_in[19];
  const float* fcb   = (const float*)d_in[20];
  float* out = (float*)d_out;

  char* p = (char*)d_ws;
  auto alloc = [&](size_t bytes)->char*{
    char* r = p; p += (bytes + 255) & ~(size_t)255; return r;
  };
  f16* w0fp   = (f16*)alloc((size_t)G_*EP_*2);       // 1.3 MB
  f16* w0rp   = (f16*)alloc((size_t)G_*EP_*2);
  f16* whf    = (f16*)alloc((size_t)G_*H_*2);        // 2 MB
  f16* whr    = (f16*)alloc((size_t)G_*H_*2);
  f16* w1i    = (f16*)alloc((size_t)G_*D1_*2);       // 4 MB
  f16* w1h    = (f16*)alloc((size_t)G_*H_*2);        // 2 MB
  float* bs0  = (float*)alloc((size_t)2*G_*4);
  float* bs1r = (float*)alloc(G_*4);
  int*   len  = (int*)alloc(B_*4);
  f16* outcat = (f16*)alloc((size_t)S_*B_*D1_*2);    // 67 MB
  f16* hxA    = (f16*)alloc((size_t)2*2*B_*H_*2);
  f16* hx1    = (f16*)alloc((size_t)2*B_*H_*2);
  float* cstate=(float*)alloc((size_t)B_*H_*4);
  float* h1f  = (float*)alloc((size_t)B_*H_*4);
  float* Mf   = (float*)alloc(2*512*4);
  float* bf   = (float*)alloc(256);
  u32* barA   = (u32*)alloc(4*S_*4);
  u32* barC   = (u32*)alloc(2*S_*4);
  // fixed ~81 MB; Z1c chunk adaptive (ws >= ~90 MB proven by round 2)
  size_t used = (size_t)(p - (char*)d_ws);
  int CH = 8;
  for (int c = 256; c >= 8; c >>= 1){
    if (used + (size_t)c*B_*G_*2 <= ws_size){ CH = c; break; }
  }
  f16* Z1c = (f16*)alloc((size_t)CH*B_*G_*2);
  const int NC = S_/CH;

  int n;
  n = G_*EP_; k_pad_w<<<(n+255)/256, 256, 0, stream>>>(wih0f, w0fp, G_, E_, EP_);
              k_pad_w<<<(n+255)/256, 256, 0, stream>>>(wih0r, w0rp, G_, E_, EP_);
  n = G_*H_;  k_f32_to_f16<<<(n+255)/256,256,0,stream>>>(whh0f, whf, n);
              k_f32_to_f16<<<(n+255)/256,256,0,stream>>>(whh0r, whr, n);
              k_f32_to_f16<<<(n+255)/256,256,0,stream>>>(whh1r, w1h, n);
  n = G_*D1_; k_f32_to_f16<<<(n+255)/256,256,0,stream>>>(wih1r, w1i, n);
  k_bias<<<8,256,0,stream>>>(bih0f, bhh0f, bs0, G_);
  k_bias<<<8,256,0,stream>>>(bih0r, bhh0r, bs0 + G_, G_);
  k_bias<<<8,256,0,stream>>>(bih1r, bhh1r, bs1r, G_);
  k_len<<<1,128,0,stream>>>(x, len);
  k_init<<<(B_*H_+255)/256,256,0,stream>>>(hxA, hx1, cstate, barA, barC);
  k_fold<<<4,256,0,stream>>>(fc1w, fc1b, fcw, fcb, Mf, bf);

  // ---- phase A: layer-0 fwd+rev, single persistent launch ----
  k_phaseA<<<dim3(2,32,2), 256, 0, stream>>>(
      x, w0fp, w0rp, whf, whr, bs0, len, hxA, outcat, barA);

  // ---- phase C: per chunk, dense Z1 GEMM then recurrence ----
  for (int cc = 0; cc < NC; ++cc){
    int t0 = S_ - (cc+1)*CH;     // chunk covers t in [t0, t0+CH), consumed descending
    k_gemm_bt<<<dim3(CH*2,32), 256, 0, stream>>>(
        outcat + (size_t)t0*B_*D1_, w1i, Z1c, bs1r, CH*B_, G_, D1_);
    k_phaseCrec<<<dim3(2,32), 256, 0, stream>>>(
        Z1c, w1h, len, hx1, cstate, h1f, barC, cc*CH, CH);
  }

  k_final<<<1,256,0,stream>>>(h1f, Mf, bf, out);
}